// Round 11
// baseline (589.848 us; speedup 1.0000x reference)
//
#include <hip/hip_runtime.h>
#include <math.h>

#define TT   16
#define BATCH 8
#define HH   64
#define WW   64
#define HWSZ 4096
#define HID  32
#define CT_STRIDE 68

typedef __bf16 bf16x8 __attribute__((ext_vector_type(8)));
typedef float  f32x4  __attribute__((ext_vector_type(4)));
typedef unsigned short u16;
typedef unsigned int   u32;
typedef unsigned long long u64;
typedef u32 u32x4 __attribute__((ext_vector_type(4)));

__device__ __forceinline__ u16 f2bf(float f) {
    union { float f; u32 u; } v; v.f = f;
    u32 r = v.u + 0x7FFF + ((v.u >> 16) & 1);   // RNE
    return (u16)(r >> 16);
}

// ---- W -> 16x16 MFMA B-frag order [tap][kc][nt(8)][lane(64)] x 16B ----
__device__ __forceinline__ void prep_w16(const float* __restrict__ W,
                                         u16* __restrict__ wf, int cinl, int idx) {
    const int lane = idx & 63, nt = (idx >> 6) & 7, kc = (idx >> 9) & 1, tap = idx >> 10;
    const int cho = nt * 16 + (lane & 15);
    const int cb  = kc * 32 + ((lane >> 4) * 8);
    u16 o[8];
#pragma unroll
    for (int j = 0; j < 8; ++j) {
        const int cin = cb + j;
        o[j] = (cin < cinl) ? f2bf(W[((size_t)cho * cinl + cin) * 9 + tap]) : (u16)0;
    }
    ((uint4*)wf)[idx] = *(uint4*)&o[0];
}

__global__ __launch_bounds__(256)
void prep_all(const float* __restrict__ x, u16* __restrict__ xbf,
              const float* __restrict__ W0, u16* __restrict__ wf0,
              const float* __restrict__ W1, u16* __restrict__ wf1) {
    const int bid = blockIdx.x, tid = threadIdx.x;
    if (bid < 2048) {
        const int p = bid * 256 + tid;           // (t*8+b)*4096 + pix
        const int tb = p >> 12, pix = p & 4095;
        const float* src = x + ((size_t)tb * 16) * HWSZ + pix;
        u16 o[16];
#pragma unroll
        for (int c = 0; c < 16; ++c) o[c] = f2bf(src[(size_t)c * HWSZ]);
        uint4* dst = (uint4*)(xbf + (size_t)p * 16);
        dst[0] = *(uint4*)&o[0];
        dst[1] = *(uint4*)&o[8];
    } else if (bid < 2084) {
        prep_w16(W0, wf0, 48, (bid - 2048) * 256 + tid);
    } else {
        prep_w16(W1, wf1, 64, (bid - 2084) * 256 + tid);
    }
}

// ---- fused ConvLSTM step v10: fat waves, M=128/wave (2 rows) ----
// 256 blocks total (1 per CU): blk<128 -> layer0, else layer1.
// Within half: b = blk>>4, y0 = (blk&15)*4 (4 output rows per block).
// Block = 4 waves: wave w -> khalf = w&1, wrow = w>>1 (rows y0+wrow*2 +{0,1}).
// Wave tile M=128 px (8 m-frags: m&3 = 16-px col group, m>>2 = row) x N=64.
// B-reuse 8x per load -> per-CU L2 weight traffic halved vs v8.
__device__ __forceinline__ void conv_step(
    const u16* __restrict__ srcX, int xch,          // pixel-major bf16 [B*4096][xch]
    const u16* __restrict__ srcH,                   // pixel-major bf16 [B*4096][32]
    const uint4* __restrict__ wf,                   // [9][2][8][64] x 16B
    const float* __restrict__ bias,                 // [128]
    float* __restrict__ cbuf,                       // [B,32,H,W] running c (in/out)
    float* __restrict__ hout, float* __restrict__ hT,
    u16* __restrict__ hbfo,
    int t0, int blk, uint4* lds4, float* ctile)
{
    const int tid = threadIdx.x;
    const int y0 = (blk & 15) * 4;
    const int b  = blk >> 4;

    // ---- T14 split: issue c-tile loads to REGISTERS first (oldest in flight) ----
    const int fr  = tid >> 1;          // 0..127: row = fyy*32 + fc
    const int fyy = fr >> 5, fc = fr & 31;
    const size_t gflat = ((size_t)(b * HID + fc) * HH + (y0 + fyy)) * WW;
    uint4 cld[8];
    if (!t0) {
#pragma unroll
        for (int j = 0; j < 8; ++j) {
            const int q = j * 2 + (tid & 1);   // uint4 idx 0..15 within row
            cld[j] = *(const uint4*)(cbuf + gflat + q * 4);
        }
    }

    // ---- stage 6 rows x 66 px x 64 cin (16B chunks), XOR-swizzled ----
    for (int q = tid; q < 3168; q += 256) {
        const int c8 = q & 7;
        const int pr = q >> 3;          // 0..395
        const int px = pr % 66;
        const int r  = pr / 66;         // 0..5  (gy = y0-1+r)
        const int gy = y0 - 1 + r;
        const int gx = px - 1;
        uint4 v = {0u, 0u, 0u, 0u};
        if (gy >= 0 && gy < HH && gx >= 0 && gx < WW) {
            const int pix = b * HWSZ + gy * WW + gx;
            const int cin8 = c8 * 8;
            if (cin8 < xch) {
                v = *(const uint4*)(srcX + (size_t)pix * xch + cin8);
            } else if (cin8 < xch + 32) {
                if (!t0) v = *(const uint4*)(srcH + (size_t)pix * 32 + (cin8 - xch));
            }
        }
        lds4[(pr * 8 + c8) ^ (px & 7)] = v;
    }
    __syncthreads();

    const int lane  = tid & 63;
    const int w     = tid >> 6;
    const int l15   = lane & 15, lhi = lane >> 4;
    const int khalf = w & 1;
    const int wrow  = w >> 1;           // row-pair: out rows y0 + wrow*2 + {0,1}

    float bv[4];
#pragma unroll
    for (int n = 0; n < 4; ++n) bv[n] = bias[n * 32 + khalf * 16 + l15];
    f32x4 acc[8][4];
#pragma unroll
    for (int m = 0; m < 8; ++m)
#pragma unroll
        for (int n = 0; n < 4; ++n)
            acc[m][n] = (f32x4){bv[n], bv[n], bv[n], bv[n]};

    const int p0 = l15 + 1;   // tile px for dx=0, col-group 0

    // group g = tap*2 + kc, g in [0,18)
    auto LOADA = [&](bf16x8* dst, int g) {
        const int tap = g >> 1, kc = g & 1;
        const int dx = tap % 3 - 1;
        const int kcell = kc * 4 + lhi;
#pragma unroll
        for (int m = 0; m < 8; ++m) {
            const int sr = wrow * 2 + (m >> 2) + tap / 3;
            const int pxt = p0 + (m & 3) * 16 + dx;
            dst[m] = __builtin_bit_cast(bf16x8,
                     lds4[(((sr * 66 + pxt) * 8) + kcell) ^ (pxt & 7)]);
        }
    };
    auto LOADB = [&](bf16x8* dst, int g) {
#pragma unroll
        for (int n = 0; n < 4; ++n)
            dst[n] = __builtin_bit_cast(bf16x8,
                     wf[((size_t)g * 8 + (khalf + 2 * n)) * 64 + lane]);
    };
    auto MFMAG = [&](const bf16x8* a, const bf16x8* bw) {
#pragma unroll
        for (int n = 0; n < 4; ++n)
#pragma unroll
            for (int m = 0; m < 8; ++m)
                acc[m][n] = __builtin_amdgcn_mfma_f32_16x16x32_bf16(
                                a[m], bw[n], acc[m][n], 0, 0, 0);
    };

    bf16x8 a0[8], a1[8], b0[4], b1[4];
    LOADA(a0, 0); LOADB(b0, 0);
    LOADA(a1, 1); LOADB(b1, 1);
#pragma unroll
    for (int g = 0; g < 18; g += 2) {
        MFMAG(a0, b0);
        if (g + 2 < 18) { LOADA(a0, g + 2); LOADB(b0, g + 2); }
        MFMAG(a1, b1);
        if (g + 3 < 18) { LOADA(a1, g + 3); LOADB(b1, g + 3); }
    }

    // ---- write the prefetched c registers into ctile, then barrier ----
    if (!t0) {
#pragma unroll
        for (int j = 0; j < 8; ++j) {
            const int q = j * 2 + (tid & 1);
            *(uint4*)(ctile + fr * CT_STRIDE + q * 4) = cld[j];
        }
    }
    __syncthreads();                    // K-loop reads done; lds4 -> htile

    float* htile = (float*)lds4;        // [128][CT_STRIDE] fp32 (34.8KB <= 50.7KB)

    // ---- LSTM pointwise epilogue (register -> LDS tiles) ----
    const int c = khalf * 16 + l15;                 // hid channel
#pragma unroll
    for (int m = 0; m < 8; ++m) {
        const int row = (wrow * 2 + (m >> 2)) * 32 + c;
#pragma unroll
        for (int rr = 0; rr < 4; ++rr) {
            const int p = (m & 3) * 16 + lhi * 4 + rr;
            const float cp = t0 ? 0.f : ctile[row * CT_STRIDE + p];
            const float iv = acc[m][0][rr], fv = acc[m][1][rr];
            const float ov = acc[m][2][rr], gv = acc[m][3][rr];
            const float ig = __builtin_amdgcn_rcpf(1.f + __expf(-iv));
            const float fg = __builtin_amdgcn_rcpf(1.f + __expf(-fv));
            const float og = __builtin_amdgcn_rcpf(1.f + __expf(-ov));
            const float gg = 1.f - 2.f * __builtin_amdgcn_rcpf(1.f + __expf(2.f * gv));
            const float cn = fg * cp + ig * gg;
            const float hn = og * (1.f - 2.f * __builtin_amdgcn_rcpf(1.f + __expf(2.f * cn)));
            ctile[row * CT_STRIDE + p] = cn;
            htile[row * CT_STRIDE + p] = hn;
        }
    }
    __syncthreads();

    // ---- flush 1: htile -> hseq[t] / hT (nt stores), ctile -> cbuf ----
#pragma unroll
    for (int j = 0; j < 8; ++j) {
        const int q = j * 2 + (tid & 1);
        const u32x4 hv = *(const u32x4*)(htile + fr * CT_STRIDE + q * 4);
        const uint4 cv = *(const uint4*)(ctile + fr * CT_STRIDE + q * 4);
        __builtin_nontemporal_store(hv, (u32x4*)(hout + gflat + q * 4));
        *(uint4*)(cbuf + gflat + q * 4) = cv;
        if (hT) __builtin_nontemporal_store(hv, (u32x4*)(hT + gflat + q * 4));
    }

    // ---- flush 2: htile -> hbf ping-pong, packed u64 coalesced stores ----
#pragma unroll
    for (int j = 0; j < 8; ++j) {
        const int idx = j * 256 + tid;       // 0..2047
        const int c4  = idx & 7;             // 4-channel group
        const int pxx = (idx >> 3) & 63;
        const int yy  = idx >> 9;            // 0..3
        u16 pk[4];
#pragma unroll
        for (int k = 0; k < 4; ++k)
            pk[k] = f2bf(htile[(yy * 32 + c4 * 4 + k) * CT_STRIDE + pxx]);
        const int pix = b * HWSZ + (y0 + yy) * WW + pxx;
        *(u64*)(hbfo + (size_t)pix * 32 + c4 * 4) = *(u64*)pk;
    }
}

__global__ __launch_bounds__(256, 1)
void fused_step(
    const u16* srcX0, const u16* srcH0, const uint4* wf0, const float* bias0,
    float* cbuf0, float* hout0, float* hT0, u16* hbfo0, int t00, int act0,
    const u16* srcX1, const u16* srcH1, const uint4* wf1, const float* bias1,
    float* cbuf1, float* hout1, float* hT1, u16* hbfo1, int t01, int act1)
{
    __shared__ uint4 lds4[3168];               // 50,688 B (A-tile, then htile)
    __shared__ float ctile[128 * CT_STRIDE];   // 34,816 B
    const int blk = blockIdx.x;
    if (blk < 128) {
        if (!act0) return;
        conv_step(srcX0, 16, srcH0, wf0, bias0, cbuf0, hout0, hT0, hbfo0, t00, blk, lds4, ctile);
    } else {
        if (!act1) return;
        conv_step(srcX1, 32, srcH1, wf1, bias1, cbuf1, hout1, hT1, hbfo1, t01, blk - 128, lds4, ctile);
    }
}

extern "C" void kernel_launch(void* const* d_in, const int* in_sizes, int n_in,
                              void* d_out, int out_size, void* d_ws, size_t ws_size,
                              hipStream_t stream) {
    const float* x  = (const float*)d_in[0];
    const float* W0 = (const float*)d_in[1];
    const float* b0 = (const float*)d_in[2];
    const float* W1 = (const float*)d_in[3];
    const float* b1 = (const float*)d_in[4];
    float* out = (float*)d_out;

    float* hseq0 = out;
    float* hseq1 = out + 16777216;
    float* h0T   = out + 33554432;
    float* c0T   = out + 34603008;   // running c, layer 0 (channel-major, in-place)
    float* h1T   = out + 35651584;
    float* c1T   = out + 36700160;   // running c, layer 1

    // ws: xbf 16,777,216 | wf0 147,456 | wf1 147,456 | hbf0[2] | hbf1[2]
    char* ws = (char*)d_ws;
    u16*  xbf = (u16*)ws;
    u16*  wf0 = (u16*)(ws + 16777216);
    u16*  wf1 = (u16*)(ws + 16777216 + 147456);
    u16*  hbf0[2] = { (u16*)(ws + 17072128), (u16*)(ws + 17072128 + 2097152) };
    u16*  hbf1[2] = { (u16*)(ws + 21266432), (u16*)(ws + 21266432 + 2097152) };

    prep_all<<<2120, 256, 0, stream>>>(x, xbf, W0, wf0, W1, wf1);

    const size_t hstep = (size_t)BATCH * HID * HWSZ;   // 1,048,576 floats
    const size_t xstep = (size_t)BATCH * HWSZ * 16;    // bf16 elems per t

    for (int d = 0; d <= TT; ++d) {
        const int t0 = (d < TT) ? d : TT - 1;      // clamped (inactive half)
        const int t1 = (d >= 1) ? d - 1 : 0;
        const int act0 = (d < TT), act1 = (d >= 1);
        fused_step<<<256, 256, 0, stream>>>(
            xbf + (size_t)t0 * xstep, hbf0[(t0 - 1) & 1],
            (const uint4*)wf0, b0, c0T,
            hseq0 + (size_t)t0 * hstep, (t0 == TT - 1 && act0) ? h0T : nullptr,
            hbf0[t0 & 1], (t0 == 0) ? 1 : 0, act0,
            hbf0[t1 & 1], hbf1[(t1 - 1) & 1],
            (const uint4*)wf1, b1, c1T,
            hseq1 + (size_t)t1 * hstep, (t1 == TT - 1 && act1) ? h1T : nullptr,
            hbf1[t1 & 1], (t1 == 0) ? 1 : 0, act1);
    }
}

// Round 12
// 261.257 us; speedup vs baseline: 2.2577x; 2.2577x over previous
//
#include <hip/hip_runtime.h>
#include <math.h>

#define TT   16
#define BATCH 8
#define HH   64
#define WW   64
#define HWSZ 4096
#define HID  32
#define CT_STRIDE 68

typedef __bf16 bf16x8 __attribute__((ext_vector_type(8)));
typedef float  f32x4  __attribute__((ext_vector_type(4)));
typedef unsigned short u16;
typedef unsigned int   u32;
typedef unsigned long long u64;
typedef u32 u32x4 __attribute__((ext_vector_type(4)));

__device__ __forceinline__ u16 f2bf(float f) {
    union { float f; u32 u; } v; v.f = f;
    u32 r = v.u + 0x7FFF + ((v.u >> 16) & 1);   // RNE
    return (u16)(r >> 16);
}

// swizzled ctile/htile index: spreads stride-68 scalar RMW across banks.
// XOR only bits 2..3 of p -> 16B blocks map to 16B blocks (flush stays aligned).
__device__ __forceinline__ int cidx(int row, int p) {
    return row * CT_STRIDE + (p ^ ((row & 3) << 2));
}

// async global->LDS, 16B per lane; lds dest = wave-uniform base + lane*16
__device__ __forceinline__ void gl2lds(const void* g, void* l) {
    __builtin_amdgcn_global_load_lds(
        (const __attribute__((address_space(1))) u32*)g,
        (__attribute__((address_space(3))) u32*)l, 16, 0, 0);
}

// ---- W -> 16x16 MFMA B-frag order [tap][kc][nt(8)][lane(64)] x 16B ----
__device__ __forceinline__ void prep_w16(const float* __restrict__ W,
                                         u16* __restrict__ wf, int cinl, int idx) {
    const int lane = idx & 63, nt = (idx >> 6) & 7, kc = (idx >> 9) & 1, tap = idx >> 10;
    const int cho = nt * 16 + (lane & 15);
    const int cb  = kc * 32 + ((lane >> 4) * 8);
    u16 o[8];
#pragma unroll
    for (int j = 0; j < 8; ++j) {
        const int cin = cb + j;
        o[j] = (cin < cinl) ? f2bf(W[((size_t)cho * cinl + cin) * 9 + tap]) : (u16)0;
    }
    ((uint4*)wf)[idx] = *(uint4*)&o[0];
}

__global__ __launch_bounds__(256)
void prep_all(const float* __restrict__ x, u16* __restrict__ xbf,
              const float* __restrict__ W0, u16* __restrict__ wf0,
              const float* __restrict__ W1, u16* __restrict__ wf1) {
    const int bid = blockIdx.x, tid = threadIdx.x;
    if (bid < 2048) {
        const int p = bid * 256 + tid;           // (t*8+b)*4096 + pix
        const int tb = p >> 12, pix = p & 4095;
        const float* src = x + ((size_t)tb * 16) * HWSZ + pix;
        u16 o[16];
#pragma unroll
        for (int c = 0; c < 16; ++c) o[c] = f2bf(src[(size_t)c * HWSZ]);
        uint4* dst = (uint4*)(xbf + (size_t)p * 16);
        dst[0] = *(uint4*)&o[0];
        dst[1] = *(uint4*)&o[8];
    } else if (bid < 2084) {
        prep_w16(W0, wf0, 48, (bid - 2048) * 256 + tid);
    } else {
        prep_w16(W1, wf1, 64, (bid - 2084) * 256 + tid);
    }
}

// ---- fused ConvLSTM step v11: v8 + global_load_lds staging + setprio + LDS swizzle ----
// Per layer-half: 256 blocks; blk -> b = blk>>5, y0 = (blk&31)*2 (2 output rows).
// Block = 4 waves: wave w -> row (w>>1), khalf (w&1). Wave tile M=64 px x N=64 ch.
__device__ __forceinline__ void conv_step(
    const u16* __restrict__ srcX, int xch,          // pixel-major bf16 [B*4096][xch]
    const u16* __restrict__ srcH,                   // pixel-major bf16 [B*4096][32]
    const uint4* __restrict__ wf,                   // [9][2][8][64] x 16B
    const float* __restrict__ bias,                 // [128]
    float* __restrict__ cbuf,                       // [B,32,H,W] running c (in/out)
    float* __restrict__ hout, float* __restrict__ hT,
    u16* __restrict__ hbfo, const u16* __restrict__ zp,
    int t0, int blk, uint4* lds4, float* ctile)
{
    const int tid = threadIdx.x;
    const int y0 = (blk & 31) * 2;
    const int b  = blk >> 5;
    const int lane = tid & 63;
    const int w    = tid >> 6;

    // ---- stage 4 rows x 66 px x 64 cin via global_load_lds (source-swizzled) ----
    // dest chunk q = pr*8 + c8d linear; content = logical chunk c8log = c8d ^ (px&7)
    // so the K-loop's read lds4[(pr*8+kcell)^(px&7)] lands on logical kcell.
    // OOB / t0-h / (c8log out of channel range) lanes read the 16B zero page.
    for (int j = w; j < 33; j += 4) {               // 33 wave-chunks of 64
        const int q  = j * 64 + lane;               // 0..2111
        const int pr = q >> 3;                      // 0..263
        const int px = pr % 66;
        const int r  = pr / 66;                     // 0..3 (gy = y0-1+r)
        const int c8log = (q & 7) ^ (px & 7);
        const int gy = y0 - 1 + r;
        const int gx = px - 1;
        const int pix = b * HWSZ + gy * WW + gx;
        const int cin8 = c8log * 8;
        const bool inb = (gy >= 0) && (gy < HH) && (gx >= 0) && (gx < WW);
        const u16* s =
            (cin8 < xch) ? (srcX + (size_t)pix * xch + cin8)
          : (cin8 < xch + 32) ? (t0 ? zp : (srcH + (size_t)pix * 32 + (cin8 - xch)))
          : zp;
        if (!inb) s = zp;
        gl2lds(s, (void*)(lds4 + j * 64));
    }

    // ---- coalesced c-tile load: cbuf channel-major -> ctile (swizzled idx) ----
    const int fr  = tid >> 2;          // 0..63
    const int fyy = fr >> 5, fc = fr & 31;
    const size_t gflat = ((size_t)(b * HID + fc) * HH + (y0 + fyy)) * WW;
    if (!t0) {
#pragma unroll
        for (int j = 0; j < 4; ++j) {
            const int q = j * 4 + (tid & 3);
            *(uint4*)(ctile + cidx(fr, q * 4)) =
                *(const uint4*)(cbuf + gflat + q * 4);
        }
    }
    __syncthreads();    // drains vmcnt(0): all global_load_lds chunks landed

    const int l15   = lane & 15, lhi = lane >> 4;
    const int khalf = w & 1;
    const int wrow  = w >> 1;           // which of the 2 output rows

    float bv[4];
#pragma unroll
    for (int n = 0; n < 4; ++n) bv[n] = bias[n * 32 + khalf * 16 + l15];
    f32x4 acc[4][4];
#pragma unroll
    for (int m = 0; m < 4; ++m)
#pragma unroll
        for (int n = 0; n < 4; ++n)
            acc[m][n] = (f32x4){bv[n], bv[n], bv[n], bv[n]};

    const int p0 = l15 + 1;   // tile px for dx=0, m=0

    // group g = tap*2 + kc, g in [0,18)
    auto LOADA = [&](bf16x8* dst, int g) {
        const int tap = g >> 1, kc = g & 1;
        const int sr = wrow + tap / 3;
        const int dx = tap % 3 - 1;
        const int kcell = kc * 4 + lhi;
#pragma unroll
        for (int m = 0; m < 4; ++m) {
            const int pxt = p0 + m * 16 + dx;
            dst[m] = __builtin_bit_cast(bf16x8,
                     lds4[(((sr * 66 + pxt) * 8) + kcell) ^ (pxt & 7)]);
        }
    };
    auto LOADB = [&](bf16x8* dst, int g) {
#pragma unroll
        for (int n = 0; n < 4; ++n)
            dst[n] = __builtin_bit_cast(bf16x8,
                     wf[((size_t)g * 8 + (khalf + 2 * n)) * 64 + lane]);
    };
    auto MFMAG = [&](const bf16x8* a, const bf16x8* bw) {
        __builtin_amdgcn_s_setprio(1);
#pragma unroll
        for (int n = 0; n < 4; ++n)
#pragma unroll
            for (int m = 0; m < 4; ++m)
                acc[m][n] = __builtin_amdgcn_mfma_f32_16x16x32_bf16(
                                a[m], bw[n], acc[m][n], 0, 0, 0);
        __builtin_amdgcn_s_setprio(0);
    };

    bf16x8 a0[4], a1[4], a2[4], b0[4], b1[4], b2[4];
    LOADA(a0, 0); LOADB(b0, 0);
    LOADA(a1, 1); LOADB(b1, 1);
    LOADA(a2, 2); LOADB(b2, 2);
#pragma unroll
    for (int g = 0; g < 18; g += 3) {
        MFMAG(a0, b0);
        if (g + 3 < 18) { LOADA(a0, g + 3); LOADB(b0, g + 3); }
        MFMAG(a1, b1);
        if (g + 4 < 18) { LOADA(a1, g + 4); LOADB(b1, g + 4); }
        MFMAG(a2, b2);
        if (g + 5 < 18) { LOADA(a2, g + 5); LOADB(b2, g + 5); }
    }

    __syncthreads();                    // lds4 A-tile no longer needed
    float* htile = (float*)lds4;        // [64][CT_STRIDE] fp32 (swizzled idx)

    // ---- LSTM pointwise epilogue (register -> LDS tiles) ----
    const int c = khalf * 16 + l15;                 // hid channel
    const int row = wrow * 32 + c;                  // transpose-tile row
#pragma unroll
    for (int m = 0; m < 4; ++m) {
#pragma unroll
        for (int rr = 0; rr < 4; ++rr) {
            const int p = m * 16 + lhi * 4 + rr;
            const int ci = cidx(row, p);
            const float cp = t0 ? 0.f : ctile[ci];
            const float iv = acc[m][0][rr], fv = acc[m][1][rr];
            const float ov = acc[m][2][rr], gv = acc[m][3][rr];
            const float ig = __builtin_amdgcn_rcpf(1.f + __expf(-iv));
            const float fg = __builtin_amdgcn_rcpf(1.f + __expf(-fv));
            const float og = __builtin_amdgcn_rcpf(1.f + __expf(-ov));
            const float gg = 1.f - 2.f * __builtin_amdgcn_rcpf(1.f + __expf(2.f * gv));
            const float cn = fg * cp + ig * gg;
            const float hn = og * (1.f - 2.f * __builtin_amdgcn_rcpf(1.f + __expf(2.f * cn)));
            ctile[ci] = cn;
            htile[ci] = hn;
        }
    }
    __syncthreads();

    // ---- flush 1: htile -> hseq[t] / hT (nt stores), ctile -> cbuf ----
#pragma unroll
    for (int j = 0; j < 4; ++j) {
        const int q = j * 4 + (tid & 3);
        const int ci = cidx(fr, q * 4);
        const u32x4 hv = *(const u32x4*)(htile + ci);
        const uint4 cv = *(const uint4*)(ctile + ci);
        __builtin_nontemporal_store(hv, (u32x4*)(hout + gflat + q * 4));
        *(uint4*)(cbuf + gflat + q * 4) = cv;
        if (hT) __builtin_nontemporal_store(hv, (u32x4*)(hT + gflat + q * 4));
    }

    // ---- flush 2: htile -> hbf ping-pong, packed u64 coalesced stores ----
#pragma unroll
    for (int j = 0; j < 4; ++j) {
        const int idx = j * 256 + tid;       // 0..1023
        const int c4  = idx & 7;             // 4-channel group
        const int pxx = (idx >> 3) & 63;
        const int yy  = idx >> 9;
        u16 pk[4];
#pragma unroll
        for (int k = 0; k < 4; ++k)
            pk[k] = f2bf(htile[cidx(yy * 32 + c4 * 4 + k, pxx)]);
        const int pix = b * HWSZ + (y0 + yy) * WW + pxx;
        *(u64*)(hbfo + (size_t)pix * 32 + c4 * 4) = *(u64*)pk;
    }
}

__global__ __launch_bounds__(256, 2)
void fused_step(
    const u16* srcX0, const u16* srcH0, const uint4* wf0, const float* bias0,
    float* cbuf0, float* hout0, float* hT0, u16* hbfo0, int t00, int act0,
    const u16* srcX1, const u16* srcH1, const uint4* wf1, const float* bias1,
    float* cbuf1, float* hout1, float* hT1, u16* hbfo1, int t01, int act1,
    const u16* zp)
{
    __shared__ uint4 lds4[2112];              // 33,792 B (A-tile, then htile)
    __shared__ float ctile[64 * CT_STRIDE];   // 17,408 B
    const int blk = blockIdx.x;
    if (blk < 256) {
        if (!act0) return;
        conv_step(srcX0, 16, srcH0, wf0, bias0, cbuf0, hout0, hT0, hbfo0, zp, t00, blk, lds4, ctile);
    } else {
        if (!act1) return;
        conv_step(srcX1, 32, srcH1, wf1, bias1, cbuf1, hout1, hT1, hbfo1, zp, t01, blk - 256, lds4, ctile);
    }
}

extern "C" void kernel_launch(void* const* d_in, const int* in_sizes, int n_in,
                              void* d_out, int out_size, void* d_ws, size_t ws_size,
                              hipStream_t stream) {
    const float* x  = (const float*)d_in[0];
    const float* W0 = (const float*)d_in[1];
    const float* b0 = (const float*)d_in[2];
    const float* W1 = (const float*)d_in[3];
    const float* b1 = (const float*)d_in[4];
    float* out = (float*)d_out;

    float* hseq0 = out;
    float* hseq1 = out + 16777216;
    float* h0T   = out + 33554432;
    float* c0T   = out + 34603008;   // running c, layer 0 (channel-major, in-place)
    float* h1T   = out + 35651584;
    float* c1T   = out + 36700160;   // running c, layer 1

    // ws: xbf 16,777,216 | wf0 147,456 | wf1 147,456 | hbf0[2] | hbf1[2] | zp 64
    char* ws = (char*)d_ws;
    u16*  xbf = (u16*)ws;
    u16*  wf0 = (u16*)(ws + 16777216);
    u16*  wf1 = (u16*)(ws + 16777216 + 147456);
    u16*  hbf0[2] = { (u16*)(ws + 17072128), (u16*)(ws + 17072128 + 2097152) };
    u16*  hbf1[2] = { (u16*)(ws + 21266432), (u16*)(ws + 21266432 + 2097152) };
    u16*  zp = (u16*)(ws + 25460736);        // 64B zero page (16B-aligned)

    (void)hipMemsetAsync(zp, 0, 64, stream);
    prep_all<<<2120, 256, 0, stream>>>(x, xbf, W0, wf0, W1, wf1);

    const size_t hstep = (size_t)BATCH * HID * HWSZ;   // 1,048,576 floats
    const size_t xstep = (size_t)BATCH * HWSZ * 16;    // bf16 elems per t

    for (int d = 0; d <= TT; ++d) {
        const int t0 = (d < TT) ? d : TT - 1;      // clamped (inactive half)
        const int t1 = (d >= 1) ? d - 1 : 0;
        const int act0 = (d < TT), act1 = (d >= 1);
        fused_step<<<512, 256, 0, stream>>>(
            xbf + (size_t)t0 * xstep, hbf0[(t0 - 1) & 1],
            (const uint4*)wf0, b0, c0T,
            hseq0 + (size_t)t0 * hstep, (t0 == TT - 1 && act0) ? h0T : nullptr,
            hbf0[t0 & 1], (t0 == 0) ? 1 : 0, act0,
            hbf0[t1 & 1], hbf1[(t1 - 1) & 1],
            (const uint4*)wf1, b1, c1T,
            hseq1 + (size_t)t1 * hstep, (t1 == TT - 1 && act1) ? h1T : nullptr,
            hbf1[t1 & 1], (t1 == 0) ? 1 : 0, act1,
            zp);
    }
}

// Round 13
// 250.643 us; speedup vs baseline: 2.3533x; 1.0423x over previous
//
#include <hip/hip_runtime.h>
#include <math.h>

#define TT   16
#define BATCH 8
#define HH   64
#define WW   64
#define HWSZ 4096
#define HID  32
#define CT_STRIDE 68

typedef __bf16 bf16x8 __attribute__((ext_vector_type(8)));
typedef float  f32x4  __attribute__((ext_vector_type(4)));
typedef unsigned short u16;
typedef unsigned int   u32;
typedef unsigned long long u64;
typedef u32 u32x4 __attribute__((ext_vector_type(4)));

__device__ __forceinline__ u16 f2bf(float f) {
    union { float f; u32 u; } v; v.f = f;
    u32 r = v.u + 0x7FFF + ((v.u >> 16) & 1);   // RNE
    return (u16)(r >> 16);
}

// swizzled ctile/htile index: spreads stride-68 scalar RMW across banks.
__device__ __forceinline__ int cidx(int row, int p) {
    return row * CT_STRIDE + (p ^ ((row & 3) << 2));
}

// async global->LDS, 16B per lane; lds dest = wave-uniform base + lane*16
__device__ __forceinline__ void gl2lds(const void* g, void* l) {
    __builtin_amdgcn_global_load_lds(
        (const __attribute__((address_space(1))) u32*)g,
        (__attribute__((address_space(3))) u32*)l, 16, 0, 0);
}

// ---- W -> tap-major K-packed MFMA B-frag order [g][nt(8)][lane(64)] x 16B ----
// k = tap*cinl + cin, groups of 32; k >= 9*cinl -> zero (padding).
__device__ __forceinline__ void prep_wp(const float* __restrict__ W,
                                        u16* __restrict__ wf, int cinl, int idx) {
    const int lane = idx & 63, nt = (idx >> 6) & 7, g = idx >> 9;
    const int cho = nt * 16 + (lane & 15);
    const int k0  = g * 32 + (lane >> 4) * 8;
    u16 o[8];
#pragma unroll
    for (int j = 0; j < 8; ++j) {
        const int k = k0 + j;
        const int tap = k / cinl;
        const int cin = k - tap * cinl;
        o[j] = (tap < 9) ? f2bf(W[((size_t)cho * cinl + cin) * 9 + tap]) : (u16)0;
    }
    ((uint4*)wf)[idx] = *(uint4*)&o[0];
}

__global__ __launch_bounds__(256)
void prep_all(const float* __restrict__ x, u16* __restrict__ xbf,
              const float* __restrict__ W0, u16* __restrict__ wf0,
              const float* __restrict__ W1, u16* __restrict__ wf1) {
    const int bid = blockIdx.x, tid = threadIdx.x;
    if (bid < 2048) {
        const int p = bid * 256 + tid;           // (t*8+b)*4096 + pix
        const int tb = p >> 12, pix = p & 4095;
        const float* src = x + ((size_t)tb * 16) * HWSZ + pix;
        u16 o[16];
#pragma unroll
        for (int c = 0; c < 16; ++c) o[c] = f2bf(src[(size_t)c * HWSZ]);
        uint4* dst = (uint4*)(xbf + (size_t)p * 16);
        dst[0] = *(uint4*)&o[0];
        dst[1] = *(uint4*)&o[8];
    } else if (bid < 2076) {                     // 28 blocks: L0, 14 groups
        prep_wp(W0, wf0, 48, (bid - 2048) * 256 + tid);
    } else if (bid < 2112) {                     // 36 blocks: L1, 18 groups
        prep_wp(W1, wf1, 64, (bid - 2076) * 256 + tid);
    }
}

// ---- fused ConvLSTM step v12: v11 + tap-major K-pack (L0: 14 groups vs 18) ----
// Per layer-half: 256 blocks; blk -> b = blk>>5, y0 = (blk&31)*2 (2 output rows).
// Block = 4 waves: wave w -> row (w>>1), khalf (w&1). Wave tile M=64 px x N=64 ch.
template<int NG, int CINL, int XCH>
__device__ __forceinline__ void conv_step(
    const u16* __restrict__ srcX,                   // pixel-major bf16 [B*4096][XCH]
    const u16* __restrict__ srcH,                   // pixel-major bf16 [B*4096][32]
    const uint4* __restrict__ wf,                   // [NG][8][64] x 16B
    const float* __restrict__ bias,                 // [128]
    float* __restrict__ cbuf,                       // [B,32,H,W] running c (in/out)
    float* __restrict__ hout, float* __restrict__ hT,
    u16* __restrict__ hbfo, const u16* __restrict__ zp,
    int t0, int blk, uint4* lds4, float* ctile)
{
    const int tid = threadIdx.x;
    const int y0 = (blk & 31) * 2;
    const int b  = blk >> 5;
    const int lane = tid & 63;
    const int w    = tid >> 6;

    // ---- stage 4 rows x 66 px x 64 cin via global_load_lds (source-swizzled) ----
    for (int j = w; j < 33; j += 4) {               // 33 wave-chunks of 64
        const int q  = j * 64 + lane;               // 0..2111
        const int pr = q >> 3;                      // 0..263
        const int px = pr % 66;
        const int r  = pr / 66;                     // 0..3 (gy = y0-1+r)
        const int c8log = (q & 7) ^ (px & 7);
        const int gy = y0 - 1 + r;
        const int gx = px - 1;
        const int pix = b * HWSZ + gy * WW + gx;
        const int cin8 = c8log * 8;
        const bool inb = (gy >= 0) && (gy < HH) && (gx >= 0) && (gx < WW);
        const u16* s =
            (cin8 < XCH) ? (srcX + (size_t)pix * XCH + cin8)
          : (cin8 < XCH + 32) ? (t0 ? zp : (srcH + (size_t)pix * 32 + (cin8 - XCH)))
          : zp;
        if (!inb) s = zp;
        gl2lds(s, (void*)(lds4 + j * 64));
    }

    // ---- coalesced c-tile load: cbuf channel-major -> ctile (swizzled idx) ----
    const int fr  = tid >> 2;          // 0..63
    const int fyy = fr >> 5, fc = fr & 31;
    const size_t gflat = ((size_t)(b * HID + fc) * HH + (y0 + fyy)) * WW;
    if (!t0) {
#pragma unroll
        for (int j = 0; j < 4; ++j) {
            const int q = j * 4 + (tid & 3);
            *(uint4*)(ctile + cidx(fr, q * 4)) =
                *(const uint4*)(cbuf + gflat + q * 4);
        }
    }
    __syncthreads();    // drains vmcnt(0): all global_load_lds chunks landed

    const int l15   = lane & 15, lhi = lane >> 4;
    const int khalf = w & 1;
    const int wrow  = w >> 1;           // which of the 2 output rows

    float bv[4];
#pragma unroll
    for (int n = 0; n < 4; ++n) bv[n] = bias[n * 32 + khalf * 16 + l15];
    f32x4 acc[4][4];
#pragma unroll
    for (int m = 0; m < 4; ++m)
#pragma unroll
        for (int n = 0; n < 4; ++n)
            acc[m][n] = (f32x4){bv[n], bv[n], bv[n], bv[n]};

    const int p0 = l15 + 1;   // tile px for dx=0, m=0

    // K-group g: per-lane k0 = g*32 + lhi*8 -> tap = k0/CINL, cin-chunk.
    // (8-elem k-slices never cross tap boundaries: 8 | CINL.)
    auto LOADA = [&](bf16x8* dst, int g) {
        const int k0 = g * 32 + lhi * 8;
        int tap = k0 / CINL;  if (tap > 8) tap = 8;   // pad lanes: B=0, any valid addr
        const int c8log = (k0 - tap * CINL) >> 3;     // 0..7
        const int ty = tap / 3;
        const int dx = tap - ty * 3 - 1;
        const int sr = wrow + ty;
#pragma unroll
        for (int m = 0; m < 4; ++m) {
            const int pxt = p0 + m * 16 + dx;
            dst[m] = __builtin_bit_cast(bf16x8,
                     lds4[(((sr * 66 + pxt) * 8) + c8log) ^ (pxt & 7)]);
        }
    };
    auto LOADB = [&](bf16x8* dst, int g) {
#pragma unroll
        for (int n = 0; n < 4; ++n)
            dst[n] = __builtin_bit_cast(bf16x8,
                     wf[((size_t)g * 8 + (khalf + 2 * n)) * 64 + lane]);
    };
    auto MFMAG = [&](const bf16x8* a, const bf16x8* bw) {
        __builtin_amdgcn_s_setprio(1);
#pragma unroll
        for (int n = 0; n < 4; ++n)
#pragma unroll
            for (int m = 0; m < 4; ++m)
                acc[m][n] = __builtin_amdgcn_mfma_f32_16x16x32_bf16(
                                a[m], bw[n], acc[m][n], 0, 0, 0);
        __builtin_amdgcn_s_setprio(0);
    };

    bf16x8 a0[4], a1[4], a2[4], b0[4], b1[4], b2[4];
    LOADB(b0, 0); LOADA(a0, 0);
    LOADB(b1, 1); LOADA(a1, 1);
    LOADB(b2, 2); LOADA(a2, 2);
#pragma unroll
    for (int g = 0; g < NG; g += 3) {
        MFMAG(a0, b0);
        if (g + 3 < NG) { LOADB(b0, g + 3); LOADA(a0, g + 3); }
        if (g + 1 < NG) {
            MFMAG(a1, b1);
            if (g + 4 < NG) { LOADB(b1, g + 4); LOADA(a1, g + 4); }
        }
        if (g + 2 < NG) {
            MFMAG(a2, b2);
            if (g + 5 < NG) { LOADB(b2, g + 5); LOADA(a2, g + 5); }
        }
    }

    __syncthreads();                    // lds4 A-tile no longer needed
    float* htile = (float*)lds4;        // [64][CT_STRIDE] fp32 (swizzled idx)

    // ---- LSTM pointwise epilogue (register -> LDS tiles) ----
    const int c = khalf * 16 + l15;                 // hid channel
    const int row = wrow * 32 + c;                  // transpose-tile row
#pragma unroll
    for (int m = 0; m < 4; ++m) {
#pragma unroll
        for (int rr = 0; rr < 4; ++rr) {
            const int p = m * 16 + lhi * 4 + rr;
            const int ci = cidx(row, p);
            const float cp = t0 ? 0.f : ctile[ci];
            const float iv = acc[m][0][rr], fv = acc[m][1][rr];
            const float ov = acc[m][2][rr], gv = acc[m][3][rr];
            const float ig = __builtin_amdgcn_rcpf(1.f + __expf(-iv));
            const float fg = __builtin_amdgcn_rcpf(1.f + __expf(-fv));
            const float og = __builtin_amdgcn_rcpf(1.f + __expf(-ov));
            const float gg = 1.f - 2.f * __builtin_amdgcn_rcpf(1.f + __expf(2.f * gv));
            const float cn = fg * cp + ig * gg;
            const float hn = og * (1.f - 2.f * __builtin_amdgcn_rcpf(1.f + __expf(2.f * cn)));
            ctile[ci] = cn;
            htile[ci] = hn;
        }
    }
    __syncthreads();

    // ---- flush 1: htile -> hseq[t] / hT (nt stores), ctile -> cbuf ----
#pragma unroll
    for (int j = 0; j < 4; ++j) {
        const int q = j * 4 + (tid & 3);
        const int ci = cidx(fr, q * 4);
        const u32x4 hv = *(const u32x4*)(htile + ci);
        const uint4 cv = *(const uint4*)(ctile + ci);
        __builtin_nontemporal_store(hv, (u32x4*)(hout + gflat + q * 4));
        *(uint4*)(cbuf + gflat + q * 4) = cv;
        if (hT) __builtin_nontemporal_store(hv, (u32x4*)(hT + gflat + q * 4));
    }

    // ---- flush 2: htile -> hbf ping-pong, packed u64 coalesced stores ----
#pragma unroll
    for (int j = 0; j < 4; ++j) {
        const int idx = j * 256 + tid;       // 0..1023
        const int c4  = idx & 7;             // 4-channel group
        const int pxx = (idx >> 3) & 63;
        const int yy  = idx >> 9;
        u16 pk[4];
#pragma unroll
        for (int k = 0; k < 4; ++k)
            pk[k] = f2bf(htile[cidx(yy * 32 + c4 * 4 + k, pxx)]);
        const int pix = b * HWSZ + (y0 + yy) * WW + pxx;
        *(u64*)(hbfo + (size_t)pix * 32 + c4 * 4) = *(u64*)pk;
    }
}

__global__ __launch_bounds__(256, 2)
void fused_step(
    const u16* srcX0, const u16* srcH0, const uint4* wf0, const float* bias0,
    float* cbuf0, float* hout0, float* hT0, u16* hbfo0, int t00, int act0,
    const u16* srcX1, const u16* srcH1, const uint4* wf1, const float* bias1,
    float* cbuf1, float* hout1, float* hT1, u16* hbfo1, int t01, int act1,
    const u16* zp)
{
    __shared__ uint4 lds4[2112];              // 33,792 B (A-tile, then htile)
    __shared__ float ctile[64 * CT_STRIDE];   // 17,408 B
    const int blk = blockIdx.x;
    if (blk < 256) {
        if (!act0) return;
        conv_step<14, 48, 16>(srcX0, srcH0, wf0, bias0, cbuf0, hout0, hT0, hbfo0, zp, t00, blk, lds4, ctile);
    } else {
        if (!act1) return;
        conv_step<18, 64, 32>(srcX1, srcH1, wf1, bias1, cbuf1, hout1, hT1, hbfo1, zp, t01, blk - 256, lds4, ctile);
    }
}

extern "C" void kernel_launch(void* const* d_in, const int* in_sizes, int n_in,
                              void* d_out, int out_size, void* d_ws, size_t ws_size,
                              hipStream_t stream) {
    const float* x  = (const float*)d_in[0];
    const float* W0 = (const float*)d_in[1];
    const float* b0 = (const float*)d_in[2];
    const float* W1 = (const float*)d_in[3];
    const float* b1 = (const float*)d_in[4];
    float* out = (float*)d_out;

    float* hseq0 = out;
    float* hseq1 = out + 16777216;
    float* h0T   = out + 33554432;
    float* c0T   = out + 34603008;   // running c, layer 0 (channel-major, in-place)
    float* h1T   = out + 35651584;
    float* c1T   = out + 36700160;   // running c, layer 1

    // ws: xbf 16,777,216 | wf0 147,456 | wf1 147,456 | hbf0[2] | hbf1[2] | zp 64
    char* ws = (char*)d_ws;
    u16*  xbf = (u16*)ws;
    u16*  wf0 = (u16*)(ws + 16777216);
    u16*  wf1 = (u16*)(ws + 16777216 + 147456);
    u16*  hbf0[2] = { (u16*)(ws + 17072128), (u16*)(ws + 17072128 + 2097152) };
    u16*  hbf1[2] = { (u16*)(ws + 21266432), (u16*)(ws + 21266432 + 2097152) };
    u16*  zp = (u16*)(ws + 25460736);        // 64B zero page (16B-aligned)

    (void)hipMemsetAsync(zp, 0, 64, stream);
    prep_all<<<2112, 256, 0, stream>>>(x, xbf, W0, wf0, W1, wf1);

    const size_t hstep = (size_t)BATCH * HID * HWSZ;   // 1,048,576 floats
    const size_t xstep = (size_t)BATCH * HWSZ * 16;    // bf16 elems per t

    for (int d = 0; d <= TT; ++d) {
        const int t0 = (d < TT) ? d : TT - 1;      // clamped (inactive half)
        const int t1 = (d >= 1) ? d - 1 : 0;
        const int act0 = (d < TT), act1 = (d >= 1);
        fused_step<<<512, 256, 0, stream>>>(
            xbf + (size_t)t0 * xstep, hbf0[(t0 - 1) & 1],
            (const uint4*)wf0, b0, c0T,
            hseq0 + (size_t)t0 * hstep, (t0 == TT - 1 && act0) ? h0T : nullptr,
            hbf0[t0 & 1], (t0 == 0) ? 1 : 0, act0,
            hbf0[t1 & 1], hbf1[(t1 - 1) & 1],
            (const uint4*)wf1, b1, c1T,
            hseq1 + (size_t)t1 * hstep, (t1 == TT - 1 && act1) ? h1T : nullptr,
            hbf1[t1 & 1], (t1 == 0) ? 1 : 0, act1,
            zp);
    }
}